// Round 7
// baseline (479.550 us; speedup 1.0000x reference)
//
#include <hip/hip_runtime.h>
#include <hip/hip_bf16.h>
#include <stdint.h>

#define BATCH 8192
#define PEP 15
#define INC 512
#define OUTC 512
#define XROW (PEP*INC)          // 7680 floats per batch row
#define WT_P_ELEMS (INC*OUTC)   // 262144 bf16 per p
#define NSTEPS 16               // K = 512 = 16 x 32

typedef float f32x4 __attribute__((ext_vector_type(4)));
typedef short s16x8 __attribute__((ext_vector_type(8)));
typedef unsigned int u32x4 __attribute__((ext_vector_type(4)));

__device__ __forceinline__ ushort f2b(float v) {
  // round-to-nearest-even fp32 -> bf16
  uint u = __float_as_uint(v);
  u += 0x7fffu + ((u >> 16) & 1u);
  return (ushort)(u >> 16);
}

// ---------------- kernel 1: W [p][k][n] fp32 -> fragment-linear bf16 (16x16x32) -------
// wt[(((p*16+ks)*32+n16)*64+l)*8+e] = bf16(W[p][ks*32+(l>>4)*8+e][n16*16+(l&15)])
// Per (ks,n16) the 64 lanes' 16B fragments are contiguous (1KB). Verified R1/R3/R4/R5.
__global__ __launch_bounds__(256) void wt_kernel(const float* __restrict__ w,
                                                 ushort* __restrict__ wt) {
  int gid = blockIdx.x * 256 + threadIdx.x;   // 15*16*32*64 = 491520 exactly
  int l   = gid & 63;
  int n16 = (gid >> 6) & 31;
  int ks  = (gid >> 11) & 15;
  int p   = gid >> 15;
  int fr = l & 15, g = l >> 4;
  const float* src = w + (size_t)p * WT_P_ELEMS + (size_t)(ks * 32 + g * 8) * OUTC + n16 * 16 + fr;
  s16x8 hv;
#pragma unroll
  for (int e = 0; e < 8; ++e) hv[e] = (short)f2b(src[(size_t)e * OUTC]);
  *(s16x8*)(wt + (size_t)gid * 8) = hv;
}

// ---------------- kernel 2: barrier-free DMA-pipelined GEMM ---------------------------
// Block = 4 waves; wave owns 64(m) x 128(n). NO __syncthreads anywhere.
// B: global_load_lds -> wave-private LDS slice, 2-deep, counted-vmcnt (24/16/0).
//    B LDS reads are INLINE-ASM ds_read_b128 so the compiler's waitcnt pass cannot
//    insert a conservative vmcnt(0) before them (R5's 12k-cycle/iter killer);
//    correctness is carried by our vmcnt + lgkmcnt(0) + sched_barrier fences (rule #18).
// A: direct global->reg fragment loads (fp32), dist-2 ping-pong, cvt at consume.
// Epilogue: per-wave LDS transpose -> full-line dwordx4 stores.
__global__ __launch_bounds__(256, 2) void gemm_kernel(const float* __restrict__ x,
                                                      const ushort* __restrict__ wt,
                                                      const float* __restrict__ bias,
                                                      float* __restrict__ out) {
  // [slot][wid][nf][lane][8] : 2*4*8*64*8*2B = 64 KB
  __shared__ ushort Bs[2][4][8][64][8];

  const int t    = threadIdx.x;
  const int lane = t & 63;
  const int wid  = t >> 6;
  const int fr   = lane & 15;     // fragment row (A) / col (B)
  const int g    = lane >> 4;     // k-group: k_local = g*8 + e (same map A and B)

  // chunked XCD swizzle (1920 blocks, 8 XCDs, 240 contiguous per XCD; bijective)
  const int bid = blockIdx.x;
  const int swz = (bid & 7) * 240 + (bid >> 3);
  const int mb  = swz & 127;
  const int p   = swz >> 7;
  const int m0  = mb * 64;

  // A fragment sources: lane reads row m0+mf*16+fr, cols ks*32 + g*8 .. +8
  const float* am[4];
#pragma unroll
  for (int mf = 0; mf < 4; ++mf)
    am[mf] = x + (size_t)(m0 + mf * 16 + fr) * XROW + p * INC + g * 8;

  // B source: fragment-linear; block (ks, n16=wid*8+q) at (ks*32 + wid*8+q)*512 + lane*8
  const ushort* bsrc = wt + (size_t)p * WT_P_ELEMS + (size_t)(wid * 8) * 512 + (size_t)lane * 8;

  f32x4 acc[4][8] = {};           // 128 acc regs
  f32x4 pa[2][4][2];              // A dist-2 ping-pong: 64 VGPR

  // ---- prologue, VMEM emission order pinned: A(0) | B(0) | A(1)
#pragma unroll
  for (int mf = 0; mf < 4; ++mf) {
    pa[0][mf][0] = *(const f32x4*)(am[mf]);
    pa[0][mf][1] = *(const f32x4*)(am[mf] + 4);
  }
  __builtin_amdgcn_sched_barrier(0);
#pragma unroll
  for (int q = 0; q < 8; ++q) {
    __builtin_amdgcn_global_load_lds(
        (const __attribute__((address_space(1))) void*)(bsrc + (size_t)q * 512),
        (__attribute__((address_space(3))) void*)(&Bs[0][wid][q][0][0]),
        16, 0, 0);
  }
  __builtin_amdgcn_sched_barrier(0);
#pragma unroll
  for (int mf = 0; mf < 4; ++mf) {
    pa[1][mf][0] = *(const f32x4*)(am[mf] + 32);
    pa[1][mf][1] = *(const f32x4*)(am[mf] + 36);
  }

#pragma unroll
  for (int ks = 0; ks < NSTEPS; ++ks) {
    const int cur = ks & 1;

    __builtin_amdgcn_sched_barrier(0);

    // (1) cvt A(ks) (compiler inserts exact counted vmcnt for pa[cur] regs)
    //     + (2) issue B(ks+1) DMA
    s16x8 af[4];
#pragma unroll
    for (int mf = 0; mf < 4; ++mf) {
      f32x4 v0 = pa[cur][mf][0], v1 = pa[cur][mf][1];
      af[mf][0] = (short)f2b(v0[0]); af[mf][1] = (short)f2b(v0[1]);
      af[mf][2] = (short)f2b(v0[2]); af[mf][3] = (short)f2b(v0[3]);
      af[mf][4] = (short)f2b(v1[0]); af[mf][5] = (short)f2b(v1[1]);
      af[mf][6] = (short)f2b(v1[2]); af[mf][7] = (short)f2b(v1[3]);
    }
    if (ks + 1 < NSTEPS) {
#pragma unroll
      for (int q = 0; q < 8; ++q) {
        __builtin_amdgcn_global_load_lds(
            (const __attribute__((address_space(1))) void*)(bsrc + (size_t)(ks + 1) * 16384 + (size_t)q * 512),
            (__attribute__((address_space(3))) void*)(&Bs[(ks + 1) & 1][wid][q][0][0]),
            16, 0, 0);
      }
    }

    __builtin_amdgcn_sched_barrier(0);

    // (3) issue A(ks+2) AFTER the B-DMA (emission order pinned by walls)
    if (ks + 2 < NSTEPS) {
#pragma unroll
      for (int mf = 0; mf < 4; ++mf) {
        pa[cur][mf][0] = *(const f32x4*)(am[mf] + (ks + 2) * 32);
        pa[cur][mf][1] = *(const f32x4*)(am[mf] + (ks + 2) * 32 + 4);
      }
    }

    // (4) counted wait: drain exactly through B(ks); keep B(ks+1)+A(ks+2) in flight
    __builtin_amdgcn_sched_barrier(0);
    if (ks < 14)       asm volatile("s_waitcnt vmcnt(24)" ::: "memory");
    else if (ks == 14) asm volatile("s_waitcnt vmcnt(16)" ::: "memory");
    else               asm volatile("s_waitcnt vmcnt(0)"  ::: "memory");
    __builtin_amdgcn_sched_barrier(0);

    // (5) B fragments via inline-asm ds_read_b128 (opaque to waitcnt pass)
    u32x4 braw[8];
#pragma unroll
    for (int nf = 0; nf < 8; ++nf) {
      uint boff = (uint)(uintptr_t)&Bs[cur][wid][nf][lane][0];
      asm volatile("ds_read_b128 %0, %1" : "=v"(braw[nf]) : "v"(boff));
    }
    asm volatile("s_waitcnt lgkmcnt(0)" ::: "memory");
    __builtin_amdgcn_sched_barrier(0);   // rule #18: fence MFMA below the lgkmcnt

    // (6) MFMA
#pragma unroll
    for (int mf = 0; mf < 4; ++mf)
#pragma unroll
      for (int nf = 0; nf < 8; ++nf)
        acc[mf][nf] = __builtin_amdgcn_mfma_f32_16x16x32_bf16(
            af[mf], __builtin_bit_cast(s16x8, braw[nf]), acc[mf][nf], 0, 0, 0);
  }

  // ---- epilogue: per-wave LDS transpose -> full-line stores ----
  // C/D layout col=lane&15, row=(lane>>4)*4+r (m89-verified).
  float bv[8];
#pragma unroll
  for (int nf = 0; nf < 8; ++nf) bv[nf] = bias[p * OUTC + wid * 128 + nf * 16 + fr];

  float* reg = (float*)&Bs[0][wid][0][0][0];   // wave-private 8KB = float[16][128]
  const int rr = lane >> 5;                    // 0..1
  const int cc = (lane & 31) * 4;              // 0..124

#pragma unroll
  for (int mf = 0; mf < 4; ++mf) {
    __builtin_amdgcn_sched_barrier(0);
#pragma unroll
    for (int nf = 0; nf < 8; ++nf)
#pragma unroll
      for (int r = 0; r < 4; ++r)
        reg[(g * 4 + r) * 128 + nf * 16 + fr] = acc[mf][nf][r] + bv[nf];
    __builtin_amdgcn_sched_barrier(0);
    asm volatile("s_waitcnt lgkmcnt(0)" ::: "memory");
    __builtin_amdgcn_sched_barrier(0);
    float* obase = out + (size_t)(m0 + mf * 16) * XROW + p * INC + wid * 128;
#pragma unroll
    for (int pass = 0; pass < 8; ++pass) {
      const int row = pass * 2 + rr;
      f32x4 v = *(const f32x4*)&reg[row * 128 + cc];
      *(f32x4*)(obase + (size_t)row * XROW + cc) = v;
    }
    __builtin_amdgcn_sched_barrier(0);
    asm volatile("s_waitcnt lgkmcnt(0)" ::: "memory");  // LDS reads landed before next-mf overwrite
    __builtin_amdgcn_sched_barrier(0);
  }
}

// ---------------- fallback (only if ws too small): naive fp32 ----------------
__global__ void naive_kernel(const float* __restrict__ x, const float* __restrict__ w,
                             const float* __restrict__ bias, float* __restrict__ out) {
  size_t i = (size_t)blockIdx.x * 256 + threadIdx.x;
  if (i >= (size_t)BATCH * PEP * OUTC) return;
  int o  = (int)(i & (OUTC - 1));
  int pp = (int)((i >> 9) % PEP);
  size_t b = i / ((size_t)PEP * OUTC);
  const float* xr = x + b * XROW + pp * INC;
  const float* wc = w + (size_t)pp * INC * OUTC + o;
  float s = bias[pp * OUTC + o];
  for (int k = 0; k < INC; ++k) s += xr[k] * wc[(size_t)k * OUTC];
  out[i] = s;
}

extern "C" void kernel_launch(void* const* d_in, const int* in_sizes, int n_in,
                              void* d_out, int out_size, void* d_ws, size_t ws_size,
                              hipStream_t stream) {
  const float* x    = (const float*)d_in[0];
  const float* w    = (const float*)d_in[1];
  const float* bias = (const float*)d_in[2];
  float* out = (float*)d_out;

  const size_t wt_bytes = (size_t)PEP * INC * OUTC * sizeof(ushort);  // 7.9 MB
  if (ws_size >= wt_bytes) {
    wt_kernel<<<1920, 256, 0, stream>>>(w, (ushort*)d_ws);
    gemm_kernel<<<1920, 256, 0, stream>>>(x, (const ushort*)d_ws, bias, out);
  } else {
    size_t total = (size_t)BATCH * PEP * OUTC;
    naive_kernel<<<(int)((total + 255) / 256), 256, 0, stream>>>(x, w, bias, out);
  }
}

// Round 8
// 191.869 us; speedup vs baseline: 2.4994x; 2.4994x over previous
//
#include <hip/hip_runtime.h>
#include <hip/hip_bf16.h>
#include <stdint.h>

#define BATCH 8192
#define PEP 15
#define INC 512
#define OUTC 512
#define XROW (PEP*INC)          // 7680 floats per batch row
#define WT_P_ELEMS (INC*OUTC)   // 262144 bf16 per p
#define NSTEPS 16               // K = 512 = 16 x 32

typedef float f32x4 __attribute__((ext_vector_type(4)));
typedef short s16x8 __attribute__((ext_vector_type(8)));

__device__ __forceinline__ ushort f2b(float v) {
  // round-to-nearest-even fp32 -> bf16
  uint u = __float_as_uint(v);
  u += 0x7fffu + ((u >> 16) & 1u);
  return (ushort)(u >> 16);
}

// ---------------- kernel 1: W [p][k][n] fp32 -> fragment-linear bf16 (16x16x32) -------
// wt[(((p*16+ks)*32+n16)*64+l)*8+e] = bf16(W[p][ks*32+(l>>4)*8+e][n16*16+(l&15)])
// Per (ks,n16) the 64 lanes' 16B fragments are contiguous (1KB). Verified R1-R6.
__global__ __launch_bounds__(256) void wt_kernel(const float* __restrict__ w,
                                                 ushort* __restrict__ wt) {
  int gid = blockIdx.x * 256 + threadIdx.x;   // 15*16*32*64 = 491520 exactly
  int l   = gid & 63;
  int n16 = (gid >> 6) & 31;
  int ks  = (gid >> 11) & 15;
  int p   = gid >> 15;
  int fr = l & 15, g = l >> 4;
  const float* src = w + (size_t)p * WT_P_ELEMS + (size_t)(ks * 32 + g * 8) * OUTC + n16 * 16 + fr;
  s16x8 hv;
#pragma unroll
  for (int e = 0; e < 8; ++e) hv[e] = (short)f2b(src[(size_t)e * OUTC]);
  *(s16x8*)(wt + (size_t)gid * 8) = hv;
}

// ---------------- kernel 2: m97-template GEMM ----------------------------------------
// Block = 4 waves, BM=64 x BN=256, BK=32; wave owns 64m x 64n (acc 64 VGPR).
// Both A (fp32, source-swizzled) and B (bf16 fragment-linear) staged via
// global_load_lds, double-buffered; ONE __syncthreads per K-step at body end
// (m97 shape: stage(ks+1) -> ds_read/cvt/MFMA(ks) -> barrier).
__global__ __launch_bounds__(256, 3) void gemm_kernel(const float* __restrict__ x,
                                                      const ushort* __restrict__ wt,
                                                      const float* __restrict__ bias,
                                                      float* __restrict__ out) {
  __shared__ float  As[2][2048];    // 2 x 8KB : [64 rows][32 k] fp32, XOR-swizzled 16B chunks
  __shared__ ushort Bsh[2][8192];   // 2 x 16KB: 16 frag-blocks x 64 lanes x 8 bf16

  const int t    = threadIdx.x;
  const int lane = t & 63;
  const int wid  = t >> 6;
  const int fr   = lane & 15;
  const int g    = lane >> 4;

  // grid: 3840 = 8 xcd * 480; within XCD: j&1 = n-half (pairs adjacent -> x L2-share)
  const int bid  = blockIdx.x;
  const int xcd  = bid & 7;
  const int j    = bid >> 3;
  const int n2   = j & 1;
  const int pair = xcd * 240 + (j >> 1);   // 0..1919 = 128 m-blocks x 15 p
  const int mb   = pair & 127;
  const int p    = pair >> 7;
  const int m0   = mb * 64;

  // ---- A DMA source (swizzled): LDS slot i of 1KB-chunk jj holds row jj*8+(i>>3),
  //      data-chunk (i&7)^((i>>3)&7) (4 floats). Read side XORs the same involution.
  const int rowoff = lane >> 3;
  const int chunk  = (lane & 7) ^ (rowoff & 7);
  const float* asrc[2];
#pragma unroll
  for (int jj = 0; jj < 2; ++jj)
    asrc[jj] = x + (size_t)(m0 + (wid * 2 + jj) * 8 + rowoff) * XROW + p * INC + chunk * 4;

  // ---- B DMA source: fragment-linear wt, n16 = n2*16 + wid*4 + q
  const ushort* bsrc = wt + (size_t)p * WT_P_ELEMS
                     + (size_t)(n2 * 16 + wid * 4) * 512 + (size_t)lane * 8;

  f32x4 acc[4][4] = {};             // [m16][nf]

  auto stage = [&](int ks, int buf) {
#pragma unroll
    for (int jj = 0; jj < 2; ++jj) {
      __builtin_amdgcn_global_load_lds(
          (const __attribute__((address_space(1))) void*)(asrc[jj] + ks * 32),
          (__attribute__((address_space(3))) void*)((char*)&As[buf][0] + (wid * 2 + jj) * 1024 + lane * 16),
          16, 0, 0);
    }
#pragma unroll
    for (int q = 0; q < 4; ++q) {
      __builtin_amdgcn_global_load_lds(
          (const __attribute__((address_space(1))) void*)(bsrc + (size_t)ks * 16384 + q * 512),
          (__attribute__((address_space(3))) void*)(&Bsh[buf][(wid * 4 + q) * 512 + lane * 8]),
          16, 0, 0);
    }
  };

  // ---- prologue
  stage(0, 0);
  __syncthreads();

  // per-lane read-side swizzle constants (R&7 == fr&7 since 16|m16*16... 16%8==0)
  const int sw0 = ((2 * g) ^ (fr & 7)) * 16;
  const int sw1 = ((2 * g + 1) ^ (fr & 7)) * 16;

#pragma unroll
  for (int ks = 0; ks < NSTEPS; ++ks) {
    const int cur = ks & 1;

    if (ks + 1 < NSTEPS) stage(ks + 1, cur ^ 1);

    // A fragments: 2x ds_read_b128 per m16 (2-way bank alias = free), cvt to bf16
    s16x8 af[4];
#pragma unroll
    for (int m16 = 0; m16 < 4; ++m16) {
      const char* rb = (const char*)&As[cur][0] + (m16 * 16 + fr) * 128;
      f32x4 lo = *(const f32x4*)(rb + sw0);
      f32x4 hi = *(const f32x4*)(rb + sw1);
      af[m16][0] = (short)f2b(lo[0]); af[m16][1] = (short)f2b(lo[1]);
      af[m16][2] = (short)f2b(lo[2]); af[m16][3] = (short)f2b(lo[3]);
      af[m16][4] = (short)f2b(hi[0]); af[m16][5] = (short)f2b(hi[1]);
      af[m16][6] = (short)f2b(hi[2]); af[m16][7] = (short)f2b(hi[3]);
    }

    // B fragments: lane-contiguous (conflict-free)
    s16x8 bf[4];
#pragma unroll
    for (int nf = 0; nf < 4; ++nf)
      bf[nf] = *(const s16x8*)&Bsh[cur][(wid * 4 + nf) * 512 + lane * 8];

#pragma unroll
    for (int m16 = 0; m16 < 4; ++m16)
#pragma unroll
      for (int nf = 0; nf < 4; ++nf)
        acc[m16][nf] = __builtin_amdgcn_mfma_f32_16x16x32_bf16(af[m16], bf[nf], acc[m16][nf], 0, 0, 0);

    __syncthreads();   // single drain point per K-step (m97 shape)
  }

  // ---- epilogue: wave-private LDS transpose -> full-line stores ----
  // C/D layout col=lane&15, row=(lane>>4)*4+r (m89-verified).
  const int n0 = n2 * 256 + wid * 64;
  float bv[4];
#pragma unroll
  for (int nf = 0; nf < 4; ++nf) bv[nf] = bias[p * OUTC + n0 + nf * 16 + fr];

  float* trans = reinterpret_cast<float*>(reinterpret_cast<char*>(&As[0][0]) + wid * 4096); // 16x64 f32
  const int er = lane >> 4;          // 0..3
  const int ec = (lane & 15) * 4;    // 0..60

#pragma unroll
  for (int m16 = 0; m16 < 4; ++m16) {
    __builtin_amdgcn_sched_barrier(0);
#pragma unroll
    for (int nf = 0; nf < 4; ++nf)
#pragma unroll
      for (int r = 0; r < 4; ++r)
        trans[(g * 4 + r) * 64 + nf * 16 + fr] = acc[m16][nf][r] + bv[nf];
    __builtin_amdgcn_sched_barrier(0);
    asm volatile("s_waitcnt lgkmcnt(0)" ::: "memory");
    __builtin_amdgcn_sched_barrier(0);
    float* ob = out + (size_t)(m0 + m16 * 16) * XROW + p * INC + n0;
#pragma unroll
    for (int pass = 0; pass < 4; ++pass) {
      const int row = pass * 4 + er;
      f32x4 v = *(const f32x4*)&trans[row * 64 + ec];
      *(f32x4*)(ob + (size_t)row * XROW + ec) = v;
    }
    __builtin_amdgcn_sched_barrier(0);
    asm volatile("s_waitcnt lgkmcnt(0)" ::: "memory");   // reads landed before overwrite
    __builtin_amdgcn_sched_barrier(0);
  }
}

// ---------------- fallback (only if ws too small): naive fp32 ----------------
__global__ void naive_kernel(const float* __restrict__ x, const float* __restrict__ w,
                             const float* __restrict__ bias, float* __restrict__ out) {
  size_t i = (size_t)blockIdx.x * 256 + threadIdx.x;
  if (i >= (size_t)BATCH * PEP * OUTC) return;
  int o  = (int)(i & (OUTC - 1));
  int pp = (int)((i >> 9) % PEP);
  size_t b = i / ((size_t)PEP * OUTC);
  const float* xr = x + b * XROW + pp * INC;
  const float* wc = w + (size_t)pp * INC * OUTC + o;
  float s = bias[pp * OUTC + o];
  for (int k = 0; k < INC; ++k) s += xr[k] * wc[(size_t)k * OUTC];
  out[i] = s;
}

extern "C" void kernel_launch(void* const* d_in, const int* in_sizes, int n_in,
                              void* d_out, int out_size, void* d_ws, size_t ws_size,
                              hipStream_t stream) {
  const float* x    = (const float*)d_in[0];
  const float* w    = (const float*)d_in[1];
  const float* bias = (const float*)d_in[2];
  float* out = (float*)d_out;

  const size_t wt_bytes = (size_t)PEP * INC * OUTC * sizeof(ushort);  // 7.9 MB
  if (ws_size >= wt_bytes) {
    wt_kernel<<<1920, 256, 0, stream>>>(w, (ushort*)d_ws);
    gemm_kernel<<<3840, 256, 0, stream>>>(x, (const ushort*)d_ws, bias, out);
  } else {
    size_t total = (size_t)BATCH * PEP * OUTC;
    naive_kernel<<<(int)((total + 255) / 256), 256, 0, stream>>>(x, w, bias, out);
  }
}